// Round 13
// baseline (173.356 us; speedup 1.0000x reference)
//
#include <hip/hip_runtime.h>
#include <cstdint>

#define B_ 16
#define C_ 1024
#define Q_ 128
#define H_ 768
#define OSTR (4 * H_)  // 3072

typedef __attribute__((ext_vector_type(8))) short bf16x8;
typedef __attribute__((ext_vector_type(4))) float f32x4;
typedef __attribute__((ext_vector_type(4))) int int4v;

__device__ __forceinline__ unsigned short f2bf(float x) {
  union { float f; unsigned u; } v; v.f = x;
  unsigned r = v.u + 0x7FFFu + ((v.u >> 16) & 1u);
  return (unsigned short)(r >> 16);
}
__device__ __forceinline__ unsigned pk2(float a, float b) {
  return (unsigned)f2bf(a) | ((unsigned)f2bf(b) << 16);
}
__device__ __forceinline__ float bf2f(unsigned short u) {
  union { unsigned u; float f; } t; t.u = ((unsigned)u) << 16; return t.f;
}

// four-segment fp32 -> bf16 (context, query, Wc, Wq) in one launch
__global__ __launch_bounds__(256) void f2bf4_kernel(
    const float* __restrict__ s0, unsigned short* __restrict__ d0, int n0,
    const float* __restrict__ s1, unsigned short* __restrict__ d1, int n1,
    const float* __restrict__ s2, unsigned short* __restrict__ d2, int n2,
    const float* __restrict__ s3, unsigned short* __restrict__ d3, int n3) {
  int i = blockIdx.x * 256 + threadIdx.x;
  const float* s;
  unsigned short* d;
  if (i < n0) { s = s0; d = d0; }
  else if ((i -= n0) < n1) { s = s1; d = d1; }
  else if ((i -= n1) < n2) { s = s2; d = d2; }
  else if ((i -= n2) < n3) { s = s3; d = d3; }
  else return;
  float4 a = ((const float4*)s)[2 * i];
  float4 b = ((const float4*)s)[2 * i + 1];
  int4v o;
  o[0] = (int)pk2(a.x, a.y); o[1] = (int)pk2(a.z, a.w);
  o[2] = (int)pk2(b.x, b.y); o[3] = (int)pk2(b.z, b.w);
  ((int4v*)d)[i] = o;
}

// Projection NT GEMM (128x128 tile, BK=32, global_load_lds, XCD-chunked swizzle).
// MODE 0: ctx proj -> bf16 ctxp (ob1) only, via LDS bf16-transpose + int4v stores.
// MODE 1: qry proj -> bf16 qryW=v*watt (ob1) + bf16 qryT PRE-SWIZZLED (ob2):
//         within each 128-row p-chunk, granule (16B) index g at row rc is stored
//         at g^(rc&7)  ->  linear gload_lds into LDS yields swizzled layout (T2/m173).
template <int MODE>
__global__ __launch_bounds__(256) void gemm_proj(
    const unsigned short* __restrict__ A, const unsigned short* __restrict__ Bm,
    const float* __restrict__ bias, unsigned short* __restrict__ ob1,
    unsigned short* __restrict__ ob2, const float* __restrict__ watt,
    int K, int qchunk) {
  __shared__ __align__(16) unsigned char smem[(MODE == 0) ? 33792 : 16384];
  unsigned short* As = (unsigned short*)smem;
  unsigned short* Ws = (unsigned short*)(smem + 8192);
  const int tid = threadIdx.x;
  const int lane = tid & 63;
  const int w = tid >> 6;
  const int orig = ((int)blockIdx.x & 7) * qchunk + ((int)blockIdx.x >> 3);
  const int wrA = (w >> 1) * 64;
  const int wcB = (w & 1) * 64;
  const int fr = lane & 15;
  const int fq = lane >> 4;
  const int gm = (orig / 6) * 128;
  const int gn = (orig % 6) * 128;
  const unsigned short* Ap = A + (size_t)gm * K;
  const unsigned short* Bp = Bm + (size_t)gn * K;

  auto stage128 = [&](const unsigned short* __restrict__ G, unsigned short* S, int k0) {
#pragma unroll
    for (int r = 0; r < 2; ++r) {
      const int c = r * 256 + tid;
      const int row = c >> 2, sub = c & 3;
      const unsigned short* g = G + (size_t)row * K + k0 + sub * 8;
      unsigned short* l = S + (size_t)(r * 256 + w * 64) * 8;  // wave-uniform base
      __builtin_amdgcn_global_load_lds(
          (const __attribute__((address_space(1))) void*)g,
          (__attribute__((address_space(3))) void*)l, 16, 0, 0);
    }
  };

  f32x4 acc[4][4];
#pragma unroll
  for (int i = 0; i < 4; ++i)
#pragma unroll
    for (int j = 0; j < 4; ++j)
#pragma unroll
      for (int e = 0; e < 4; ++e) acc[i][j][e] = 0.f;

  for (int k0 = 0; k0 < K; k0 += 32) {
    stage128(Ap, As, k0);
    stage128(Bp, Ws, k0);
    __syncthreads();
    bf16x8 af[4], wf[4];
#pragma unroll
    for (int i = 0; i < 4; ++i)
      af[i] = *(const bf16x8*)(As + (wrA + i * 16 + fr) * 32 + fq * 8);
#pragma unroll
    for (int j = 0; j < 4; ++j)
      wf[j] = *(const bf16x8*)(Ws + (wcB + j * 16 + fr) * 32 + fq * 8);
#pragma unroll
    for (int i = 0; i < 4; ++i)
#pragma unroll
      for (int j = 0; j < 4; ++j)
        acc[i][j] = __builtin_amdgcn_mfma_f32_16x16x32_bf16(af[i], wf[j], acc[i][j], 0, 0, 0);
    __syncthreads();
  }

  if constexpr (MODE == 0) {
    // bf16 transpose in LDS -> coalesced int4v stores of ctxp
    unsigned short* tr16 = (unsigned short*)smem;
    float bj[4];
#pragma unroll
    for (int j = 0; j < 4; ++j) bj[j] = bias[gn + wcB + j * 16 + fr];
#pragma unroll
    for (int i = 0; i < 4; ++i)
#pragma unroll
      for (int j = 0; j < 4; ++j)
#pragma unroll
        for (int r = 0; r < 4; ++r)
          tr16[(wrA + i * 16 + fq * 4 + r) * 132 + wcB + j * 16 + fr] =
              f2bf(acc[i][j][r] + bj[j]);
    __syncthreads();
#pragma unroll
    for (int k = 0; k < 8; ++k) {
      const int f = k * 256 + tid;
      const int row = f >> 4, c8 = (f & 15) << 3;
      int4v v = *(const int4v*)&tr16[row * 132 + c8];
      *(int4v*)&ob1[(size_t)(gm + row) * H_ + gn + c8] = v;
    }
  } else {
#pragma unroll
    for (int i = 0; i < 4; ++i) {
#pragma unroll
      for (int j = 0; j < 4; ++j) {
        const int n = gn + wcB + j * 16 + fr;
        const float bias_n = bias[n];
        const float wv = watt[n];
        ushort4 t4;
#pragma unroll
        for (int r = 0; r < 4; ++r) {
          const size_t m = (size_t)gm + wrA + i * 16 + fq * 4 + r;
          float v = acc[i][j][r] + bias_n;
          ob1[m * H_ + n] = f2bf(v * wv);
          (&t4.x)[r] = f2bf(v);
        }
        const int bidx = gm >> 7;
        const int q0 = wrA + i * 16 + fq * 4;
        // pre-swizzled qryT store: chunk-local row rc, granule g=q0>>3 -> g^(rc&7)
        const int rc = n & 127;
        const size_t cbase = ((size_t)bidx * H_ + (n & ~127)) * Q_;
        const int off = rc * 128 + ((((q0 >> 3) ^ (rc & 7)) << 3) | (q0 & 7));
        *(ushort4*)(ob2 + cbase + off) = t4;
      }
    }
  }
}

// Fused attention: per block (batch bb, 64 ctx rows):
//   sim K-loop (ctxp @ qryW^T) -> in-reg softmax -> alpha in LDS ->
//   6 PV chunks: stage swizzled qryT (32KB linear) -> MFMA -> fp32 transpose ->
//   coalesced writes of ctx / a / c=ctx*a output sections. Also writes q2c.
__global__ __launch_bounds__(256) void attn_fused(
    const unsigned short* __restrict__ ctxp, const unsigned short* __restrict__ qryW,
    const unsigned short* __restrict__ qryT, const float* __restrict__ cmask,
    const float* __restrict__ qmask, float* __restrict__ q2c,
    float* __restrict__ out32) {
  __shared__ __align__(16) unsigned char S[33792];      // staging / transpose
  __shared__ __align__(16) unsigned short P[64 * 132];  // alpha (bf16)
  __shared__ float pmS[2][64];
  __shared__ float psS[2][64];
  const int tid = threadIdx.x;
  const int lane = tid & 63;
  const int w = tid >> 6;
  const int fr = lane & 15;
  const int fq = lane >> 4;
  const int orig = ((int)blockIdx.x & 7) * 32 + ((int)blockIdx.x >> 3);
  const int bb = orig >> 4;
  const int gm = bb * C_ + (orig & 15) * 64;
  const int wrA = (w >> 1) * 32;  // 2 row-frags (64 rows / 2 wave-rows)
  const int wcB = (w & 1) * 64;
  const unsigned short* Ap = ctxp + (size_t)gm * H_;
  const unsigned short* Bp = qryW + (size_t)bb * Q_ * H_;
  unsigned short* Su = (unsigned short*)S;

  // ---- sim: acc[i][j] = ctx(64 rows) @ qryW(128 q)^T over K=768 ----
  f32x4 acc[2][4];
#pragma unroll
  for (int i = 0; i < 2; ++i)
#pragma unroll
    for (int j = 0; j < 4; ++j)
#pragma unroll
      for (int e = 0; e < 4; ++e) acc[i][j][e] = 0.f;

  for (int k0 = 0; k0 < H_; k0 += 32) {
    {  // stage A: 64 rows x 32k = 4KB
      const int row = tid >> 2, sub = tid & 3;
      const unsigned short* g = Ap + (size_t)row * H_ + k0 + sub * 8;
      unsigned short* l = Su + (size_t)(w * 64) * 8;
      __builtin_amdgcn_global_load_lds(
          (const __attribute__((address_space(1))) void*)g,
          (__attribute__((address_space(3))) void*)l, 16, 0, 0);
    }
#pragma unroll
    for (int r = 0; r < 2; ++r) {  // stage B: 128 rows x 32k = 8KB at +4KB
      const int c = r * 256 + tid;
      const int row = c >> 2, sub = c & 3;
      const unsigned short* g = Bp + (size_t)row * H_ + k0 + sub * 8;
      unsigned short* l = Su + 2048 + (size_t)(r * 256 + w * 64) * 8;
      __builtin_amdgcn_global_load_lds(
          (const __attribute__((address_space(1))) void*)g,
          (__attribute__((address_space(3))) void*)l, 16, 0, 0);
    }
    __syncthreads();
    bf16x8 af[2], wf[4];
#pragma unroll
    for (int i = 0; i < 2; ++i)
      af[i] = *(const bf16x8*)(Su + (wrA + i * 16 + fr) * 32 + fq * 8);
#pragma unroll
    for (int j = 0; j < 4; ++j)
      wf[j] = *(const bf16x8*)(Su + 2048 + (wcB + j * 16 + fr) * 32 + fq * 8);
#pragma unroll
    for (int i = 0; i < 2; ++i)
#pragma unroll
      for (int j = 0; j < 4; ++j)
        acc[i][j] = __builtin_amdgcn_mfma_f32_16x16x32_bf16(af[i], wf[j], acc[i][j], 0, 0, 0);
    __syncthreads();
  }

  // ---- softmax over q (128-wide, split across wave pairs) -> alpha in P ----
  {
#pragma unroll
    for (int i = 0; i < 2; ++i)
#pragma unroll
      for (int r = 0; r < 4; ++r) {
        float mx = acc[i][0][r];
#pragma unroll
        for (int j = 1; j < 4; ++j) mx = fmaxf(mx, acc[i][j][r]);
        mx = fmaxf(mx, __shfl_xor(mx, 1));
        mx = fmaxf(mx, __shfl_xor(mx, 2));
        mx = fmaxf(mx, __shfl_xor(mx, 4));
        mx = fmaxf(mx, __shfl_xor(mx, 8));
        if (fr == 0) pmS[w & 1][wrA + i * 16 + fq * 4 + r] = mx;
      }
    __syncthreads();
    float qm[4];
#pragma unroll
    for (int j = 0; j < 4; ++j) qm[j] = qmask[bb * Q_ + wcB + j * 16 + fr];
#pragma unroll
    for (int i = 0; i < 2; ++i)
#pragma unroll
      for (int r = 0; r < 4; ++r) {
        const int lr = wrA + i * 16 + fq * 4 + r;
        const float M = fmaxf(pmS[0][lr], pmS[1][lr]);
        if ((w & 1) == 0 && fr == 0) q2c[gm + lr] = M;  // b_att cancels
        float s = 0.f;
#pragma unroll
        for (int j = 0; j < 4; ++j) {
          acc[i][j][r] = __expf(acc[i][j][r] - M);
          s += acc[i][j][r];
        }
        s += __shfl_xor(s, 1); s += __shfl_xor(s, 2);
        s += __shfl_xor(s, 4); s += __shfl_xor(s, 8);
        if (fr == 0) psS[w & 1][lr] = s;
      }
    __syncthreads();
#pragma unroll
    for (int i = 0; i < 2; ++i)
#pragma unroll
      for (int r = 0; r < 4; ++r) {
        const int lr = wrA + i * 16 + fq * 4 + r;
        const float S2 = psS[0][lr] + psS[1][lr];
        const float inv = cmask[gm + lr] / S2;
#pragma unroll
        for (int j = 0; j < 4; ++j)
          P[lr * 132 + wcB + j * 16 + fr] = f2bf(acc[i][j][r] * inv * qm[j]);
      }
  }
  __syncthreads();  // P visible; S free

  // alpha A-fragments once (reused for all 6 chunks)
  bf16x8 paf[2][4];
#pragma unroll
  for (int i = 0; i < 2; ++i)
#pragma unroll
    for (int kk = 0; kk < 4; ++kk)
      paf[i][kk] = *(const bf16x8*)&P[(wrA + i * 16 + fr) * 132 + kk * 32 + fq * 8];

  // ---- PV chunks: out cols gn..gn+127, all 3 sections + ctx ----
  const unsigned short* Tb = qryT + (size_t)bb * H_ * Q_;
  for (int ch = 0; ch < 6; ++ch) {
    const int gn = ch * 128;
    // stage swizzled qryT chunk: straight 32KB linear copy
#pragma unroll
    for (int it = 0; it < 8; ++it) {
      const unsigned short* g = Tb + (size_t)gn * Q_ + it * 2048 + tid * 8;
      unsigned short* l = Su + (size_t)(it * 2048) + (size_t)(w * 64) * 8;
      __builtin_amdgcn_global_load_lds(
          (const __attribute__((address_space(1))) void*)g,
          (__attribute__((address_space(3))) void*)l, 16, 0, 0);
    }
    // ctxp tile prefetch in output layout
    ushort4 cxr[8];
#pragma unroll
    for (int k = 0; k < 8; ++k) {
      const int f = k * 256 + tid;
      const int row = f >> 5, c4 = (f & 31) << 2;
      cxr[k] = *(const ushort4*)&ctxp[(size_t)(gm + row) * H_ + gn + c4];
    }
    __syncthreads();  // chunk staged
    f32x4 pac[2][4];
#pragma unroll
    for (int i = 0; i < 2; ++i)
#pragma unroll
      for (int j = 0; j < 4; ++j)
#pragma unroll
        for (int e = 0; e < 4; ++e) pac[i][j][e] = 0.f;
#pragma unroll
    for (int kk = 0; kk < 4; ++kk) {
      bf16x8 wf[4];
#pragma unroll
      for (int j = 0; j < 4; ++j) {
        const int rp = wcB + j * 16 + fr;
        wf[j] = *(const bf16x8*)(Su + rp * 128 + (((kk * 4 + fq) ^ (rp & 7)) << 3));
      }
#pragma unroll
      for (int i = 0; i < 2; ++i)
#pragma unroll
        for (int j = 0; j < 4; ++j)
          pac[i][j] = __builtin_amdgcn_mfma_f32_16x16x32_bf16(paf[i][kk], wf[j], pac[i][j], 0, 0, 0);
    }
    __syncthreads();  // MFMA reads done; S reusable as transpose buffer
    float* tr = (float*)S;
#pragma unroll
    for (int i = 0; i < 2; ++i)
#pragma unroll
      for (int j = 0; j < 4; ++j)
#pragma unroll
        for (int r = 0; r < 4; ++r)
          tr[(wrA + i * 16 + fq * 4 + r) * 132 + wcB + j * 16 + fr] = pac[i][j][r];
    __syncthreads();  // transpose visible
#pragma unroll
    for (int k = 0; k < 8; ++k) {
      const int f = k * 256 + tid;
      const int row = f >> 5, c4 = (f & 31) << 2;
      float4 av = *(const float4*)&tr[row * 132 + c4];
      const ushort4 cu = cxr[k];
      const float cx0 = bf2f(cu.x), cx1 = bf2f(cu.y), cx2 = bf2f(cu.z), cx3 = bf2f(cu.w);
      float* rowp = out32 + (size_t)(gm + row) * OSTR + gn;
      float4 cxv; cxv.x = cx0; cxv.y = cx1; cxv.z = cx2; cxv.w = cx3;
      *(float4*)&rowp[c4] = cxv;
      *(float4*)&rowp[H_ + c4] = av;
      float4 cc;
      cc.x = cx0 * av.x; cc.y = cx1 * av.y; cc.z = cx2 * av.z; cc.w = cx3 * av.w;
      *(float4*)&rowp[2 * H_ + c4] = cc;
    }
    __syncthreads();  // store LDS-reads done; safe to restage S
  }
}

// beta softmax over c + bvec (LDS) + d-section sweep: d = ctx*bvec
__global__ __launch_bounds__(256) void beta_d_kernel(
    const unsigned short* __restrict__ ctxp, const float* __restrict__ q2c,
    const float* __restrict__ cmask, float* __restrict__ out32) {
  __shared__ float sh[C_];
  __shared__ float red[256];
  __shared__ float bb64[64];
  const int tid = threadIdx.x;
  const int b = blockIdx.x / 12;
  const int p0 = (blockIdx.x % 12) * 64;
  float v[4];
  float lm = -1e30f;
#pragma unroll
  for (int i = 0; i < 4; ++i) {
    v[i] = q2c[b * C_ + i * 256 + tid];
    lm = fmaxf(lm, v[i]);
  }
  red[tid] = lm;
  __syncthreads();
  for (int off = 128; off > 0; off >>= 1) {
    if (tid < off) red[tid] = fmaxf(red[tid], red[tid + off]);
    __syncthreads();
  }
  const float m = red[0];
  __syncthreads();
  float ls = 0.f;
#pragma unroll
  for (int i = 0; i < 4; ++i) {
    float e = __expf(v[i] - m);
    sh[i * 256 + tid] = e * cmask[b * C_ + i * 256 + tid];
    ls += e;
  }
  red[tid] = ls;
  __syncthreads();
  for (int off = 128; off > 0; off >>= 1) {
    if (tid < off) red[tid] += red[tid + off];
    __syncthreads();
  }
  const float denom = red[0];
  const int pp = tid & 63;
  const int cg = tid >> 6;
  const unsigned short* base = ctxp + ((size_t)(b * C_ + cg)) * H_ + p0 + pp;
  float acc = 0.f;
#pragma unroll 4
  for (int c = cg; c < C_; c += 4) {
    acc += sh[c] * bf2f(*base);
    base += (size_t)4 * H_;
  }
  __syncthreads();
  red[tid] = acc;
  __syncthreads();
  if (tid < 64)
    bb64[tid] = (red[tid] + red[tid + 64] + red[tid + 128] + red[tid + 192]) / denom;
  __syncthreads();
  // d sweep: out[b,c,3H+p0+pp] = ctx * bvec  (ctxp is L2/L3-hot)
  const float bv = bb64[pp];
  float* b2 = out32 + ((size_t)(b * C_ + cg)) * OSTR + 3 * H_ + p0 + pp;
  const unsigned short* cb = ctxp + ((size_t)(b * C_ + cg)) * H_ + p0 + pp;
#pragma unroll 4
  for (int c = cg; c < C_; c += 4) {
    *b2 = bf2f(*cb) * bv;
    b2 += (size_t)4 * OSTR;
    cb += (size_t)4 * H_;
  }
}

extern "C" void kernel_launch(void* const* d_in, const int* in_sizes, int n_in,
                              void* d_out, int out_size, void* d_ws, size_t ws_size,
                              hipStream_t stream) {
  const float* context = (const float*)d_in[0];
  const float* cmask   = (const float*)d_in[1];
  const float* query   = (const float*)d_in[2];
  const float* qmask   = (const float*)d_in[3];
  const float* Wc      = (const float*)d_in[4];
  const float* bc      = (const float*)d_in[5];
  const float* Wq      = (const float*)d_in[6];
  const float* bq      = (const float*)d_in[7];
  const float* w_att   = (const float*)d_in[8];
  float* out = (float*)d_out;

  unsigned short* ws_ctxb = (unsigned short*)d_ws;
  unsigned short* ws_qinb = ws_ctxb + (size_t)B_ * C_ * H_;
  unsigned short* ws_Wcb  = ws_qinb + (size_t)B_ * Q_ * H_;
  unsigned short* ws_Wqb  = ws_Wcb + (size_t)H_ * H_;
  unsigned short* ws_qryW = ws_Wqb + (size_t)H_ * H_;
  unsigned short* ws_qryT = ws_qryW + (size_t)B_ * Q_ * H_;
  unsigned short* ws_ctxp = ws_qryT + (size_t)B_ * H_ * Q_;
  float* ws_q2c = (float*)(ws_ctxp + (size_t)B_ * C_ * H_);

  {
    const int n0 = B_ * C_ * H_ / 8;
    const int n1 = B_ * Q_ * H_ / 8;
    const int n2 = H_ * H_ / 8;
    const int n3 = n2;
    const int tot = n0 + n1 + n2 + n3;
    f2bf4_kernel<<<(tot + 255) / 256, 256, 0, stream>>>(
        context, ws_ctxb, n0, query, ws_qinb, n1, Wc, ws_Wcb, n2, Wq, ws_Wqb, n3);
  }
  // qry projection: qryW (w_att folded) + pre-swizzled qryT. 96 blocks.
  gemm_proj<1><<<96, 256, 0, stream>>>(
      ws_qinb, ws_Wqb, bq, ws_qryW, ws_qryT, w_att, H_, 12);
  // ctx projection -> bf16 ctxp. 768 blocks.
  gemm_proj<0><<<768, 256, 0, stream>>>(
      ws_ctxb, ws_Wcb, bc, ws_ctxp, nullptr, nullptr, H_, 96);
  // fused attention: sim+softmax+PV; writes ctx/a/c sections + q2c. 256 blocks.
  attn_fused<<<256, 256, 0, stream>>>(
      ws_ctxp, ws_qryW, ws_qryT, cmask, qmask, ws_q2c, out);
  // beta softmax + bvec + d section. 192 blocks.
  beta_d_kernel<<<B_ * 12, 256, 0, stream>>>(ws_ctxp, ws_q2c, cmask, out);
}

// Round 14
// 155.091 us; speedup vs baseline: 1.1178x; 1.1178x over previous
//
#include <hip/hip_runtime.h>
#include <cstdint>

#define B_ 16
#define C_ 1024
#define Q_ 128
#define H_ 768
#define OSTR (4 * H_)  // 3072

typedef __attribute__((ext_vector_type(8))) short bf16x8;
typedef __attribute__((ext_vector_type(4))) float f32x4;
typedef __attribute__((ext_vector_type(4))) int int4v;

__device__ __forceinline__ unsigned short f2bf(float x) {
  union { float f; unsigned u; } v; v.f = x;
  unsigned r = v.u + 0x7FFFu + ((v.u >> 16) & 1u);
  return (unsigned short)(r >> 16);
}
__device__ __forceinline__ unsigned pk2(float a, float b) {
  return (unsigned)f2bf(a) | ((unsigned)f2bf(b) << 16);
}
__device__ __forceinline__ float bf2f(unsigned short u) {
  union { unsigned u; float f; } t; t.u = ((unsigned)u) << 16; return t.f;
}

// four-segment fp32 -> bf16 (context, query, Wc, Wq); NT loads (sources are
// dead after conversion -> don't pollute L2/L3 ahead of the GEMMs).
__global__ __launch_bounds__(256) void f2bf4_kernel(
    const float* __restrict__ s0, unsigned short* __restrict__ d0, int n0,
    const float* __restrict__ s1, unsigned short* __restrict__ d1, int n1,
    const float* __restrict__ s2, unsigned short* __restrict__ d2, int n2,
    const float* __restrict__ s3, unsigned short* __restrict__ d3, int n3) {
  int i = blockIdx.x * 256 + threadIdx.x;
  const float* s;
  unsigned short* d;
  if (i < n0) { s = s0; d = d0; }
  else if ((i -= n0) < n1) { s = s1; d = d1; }
  else if ((i -= n1) < n2) { s = s2; d = d2; }
  else if ((i -= n2) < n3) { s = s3; d = d3; }
  else return;
  f32x4 a = __builtin_nontemporal_load((const f32x4*)s + 2 * i);
  f32x4 b = __builtin_nontemporal_load((const f32x4*)s + 2 * i + 1);
  int4v o;
  o[0] = (int)pk2(a[0], a[1]); o[1] = (int)pk2(a[2], a[3]);
  o[2] = (int)pk2(b[0], b[1]); o[3] = (int)pk2(b[2], b[3]);
  ((int4v*)d)[i] = o;
}

// Unified NT GEMM, global_load_lds staging, bijective XCD-chunked swizzle.
// MODE 0: ctx proj (128x128) -> bf16 ctxp ONLY (LDS bf16-transpose, int4v stores)
// MODE 1: qry proj (128x128) -> bf16 qryW=v*watt (ob1) + bf16 qryT (ob2)
// MODE 2: sim (64x128, full q) -> fused row-softmax -> bf16 alpha (ob1) + q2c
template <int MODE>
__global__ __launch_bounds__(256) void gemm_uni(
    const unsigned short* __restrict__ A, const unsigned short* __restrict__ Bm,
    const float* __restrict__ bias, unsigned short* __restrict__ ob1,
    unsigned short* __restrict__ ob2, const float* __restrict__ watt,
    const float* __restrict__ cmask, const float* __restrict__ qmask,
    float* __restrict__ q2c, int K, int qchunk) {
  __shared__ __align__(16) unsigned char smem[(MODE == 0) ? 33792 : 16384];
  __shared__ float pmS[2][64];
  __shared__ float psS[2][64];
  constexpr int AROWS = (MODE < 2) ? 128 : 64;  // A-tile rows
  constexpr int MI = (MODE < 2) ? 4 : 2;        // row frags per wave
  unsigned short* As = (unsigned short*)smem;
  unsigned short* Ws = (unsigned short*)(smem + ((MODE < 2) ? 8192 : 4096));
  const int tid = threadIdx.x;
  const int lane = tid & 63;
  const int w = tid >> 6;
  const int orig = ((int)blockIdx.x & 7) * qchunk + ((int)blockIdx.x >> 3);
  const int wrA = (w >> 1) * (AROWS / 2);
  const int wcB = (w & 1) * 64;
  const int fr = lane & 15;
  const int fq = lane >> 4;

  int gm, gn, bb;
  const unsigned short *Ap, *Bp;
  if constexpr (MODE == 0 || MODE == 1) {
    gm = (orig / 6) * 128; gn = (orig % 6) * 128; bb = 0;
    Ap = A + (size_t)gm * K; Bp = Bm + (size_t)gn * K;
  } else {
    bb = orig >> 4; gm = bb * C_ + (orig & 15) * 64; gn = 0;
    Ap = A + (size_t)gm * K; Bp = Bm + (size_t)bb * Q_ * K;
  }

  auto stage128 = [&](const unsigned short* __restrict__ G, unsigned short* S, int k0) {
#pragma unroll
    for (int r = 0; r < 2; ++r) {
      const int c = r * 256 + tid;
      const int row = c >> 2, sub = c & 3;
      const unsigned short* g = G + (size_t)row * K + k0 + sub * 8;
      unsigned short* l = S + (size_t)(r * 256 + w * 64) * 8;  // wave-uniform base
      __builtin_amdgcn_global_load_lds(
          (const __attribute__((address_space(1))) void*)g,
          (__attribute__((address_space(3))) void*)l, 16, 0, 0);
    }
  };
  auto stage64 = [&](const unsigned short* __restrict__ G, unsigned short* S, int k0) {
    const int c = tid;
    const int row = c >> 2, sub = c & 3;
    const unsigned short* g = G + (size_t)row * K + k0 + sub * 8;
    unsigned short* l = S + (size_t)(w * 64) * 8;  // wave-uniform base
    __builtin_amdgcn_global_load_lds(
        (const __attribute__((address_space(1))) void*)g,
        (__attribute__((address_space(3))) void*)l, 16, 0, 0);
  };

  f32x4 acc[MI][4];
#pragma unroll
  for (int i = 0; i < MI; ++i)
#pragma unroll
    for (int j = 0; j < 4; ++j)
#pragma unroll
      for (int e = 0; e < 4; ++e) acc[i][j][e] = 0.f;

  for (int k0 = 0; k0 < K; k0 += 32) {
    if constexpr (MODE < 2) stage128(Ap, As, k0); else stage64(Ap, As, k0);
    stage128(Bp, Ws, k0);
    __syncthreads();
    bf16x8 af[MI], wf[4];
#pragma unroll
    for (int i = 0; i < MI; ++i)
      af[i] = *(const bf16x8*)(As + (wrA + i * 16 + fr) * 32 + fq * 8);
#pragma unroll
    for (int j = 0; j < 4; ++j)
      wf[j] = *(const bf16x8*)(Ws + (wcB + j * 16 + fr) * 32 + fq * 8);
#pragma unroll
    for (int i = 0; i < MI; ++i)
#pragma unroll
      for (int j = 0; j < 4; ++j)
        acc[i][j] = __builtin_amdgcn_mfma_f32_16x16x32_bf16(af[i], wf[j], acc[i][j], 0, 0, 0);
    __syncthreads();
  }

  if constexpr (MODE == 0) {
    // bf16 transpose in LDS -> coalesced int4v stores of ctxp only
    unsigned short* tr16 = (unsigned short*)smem;
    float bj[4];
#pragma unroll
    for (int j = 0; j < 4; ++j) bj[j] = bias[gn + wcB + j * 16 + fr];
#pragma unroll
    for (int i = 0; i < 4; ++i)
#pragma unroll
      for (int j = 0; j < 4; ++j)
#pragma unroll
        for (int r = 0; r < 4; ++r)
          tr16[(wrA + i * 16 + fq * 4 + r) * 132 + wcB + j * 16 + fr] =
              f2bf(acc[i][j][r] + bj[j]);
    __syncthreads();
#pragma unroll
    for (int k = 0; k < 8; ++k) {
      const int f = k * 256 + tid;
      const int row = f >> 4, c8 = (f & 15) << 3;
      int4v v = *(const int4v*)&tr16[row * 132 + c8];
      *(int4v*)&ob1[(size_t)(gm + row) * H_ + gn + c8] = v;
    }
  } else if constexpr (MODE == 1) {
#pragma unroll
    for (int i = 0; i < 4; ++i) {
#pragma unroll
      for (int j = 0; j < 4; ++j) {
        const int n = gn + wcB + j * 16 + fr;
        const float bias_n = bias[n];
        const float wv = watt[n];
        ushort4 t4;
#pragma unroll
        for (int r = 0; r < 4; ++r) {
          const size_t m = (size_t)gm + wrA + i * 16 + fq * 4 + r;
          float v = acc[i][j][r] + bias_n;
          ob1[m * H_ + n] = f2bf(v * wv);
          (&t4.x)[r] = f2bf(v);
        }
        const int bidx = gm >> 7;
        const int q0 = wrA + i * 16 + fq * 4;
        *(ushort4*)(ob2 + ((size_t)bidx * H_ + n) * Q_ + q0) = t4;
      }
    }
  } else {  // MODE 2: fused row-softmax over the full 128-wide q dim
    float red[MI][4];
#pragma unroll
    for (int i = 0; i < MI; ++i)
#pragma unroll
      for (int r = 0; r < 4; ++r) {
        float mx = acc[i][0][r];
#pragma unroll
        for (int j = 1; j < 4; ++j) mx = fmaxf(mx, acc[i][j][r]);
        mx = fmaxf(mx, __shfl_xor(mx, 1));
        mx = fmaxf(mx, __shfl_xor(mx, 2));
        mx = fmaxf(mx, __shfl_xor(mx, 4));
        mx = fmaxf(mx, __shfl_xor(mx, 8));
        if (fr == 0) pmS[w & 1][wrA + i * 16 + fq * 4 + r] = mx;
      }
    __syncthreads();
    float qm[4];
#pragma unroll
    for (int j = 0; j < 4; ++j) qm[j] = qmask[bb * Q_ + wcB + j * 16 + fr];
#pragma unroll
    for (int i = 0; i < MI; ++i)
#pragma unroll
      for (int r = 0; r < 4; ++r) {
        const int lr = wrA + i * 16 + fq * 4 + r;
        const float M = fmaxf(pmS[0][lr], pmS[1][lr]);
        if ((w & 1) == 0 && fr == 0) q2c[gm + lr] = M;  // b_att cancels in both softmaxes
        float s = 0.f;
#pragma unroll
        for (int j = 0; j < 4; ++j) {
          acc[i][j][r] = __expf(acc[i][j][r] - M);
          s += acc[i][j][r];
        }
        s += __shfl_xor(s, 1); s += __shfl_xor(s, 2);
        s += __shfl_xor(s, 4); s += __shfl_xor(s, 8);
        if (fr == 0) psS[w & 1][lr] = s;
      }
    __syncthreads();
#pragma unroll
    for (int i = 0; i < MI; ++i)
#pragma unroll
      for (int r = 0; r < 4; ++r) {
        const int lr = wrA + i * 16 + fq * 4 + r;
        const float S = psS[0][lr] + psS[1][lr];
        const float inv = cmask[gm + lr] / S;
#pragma unroll
        for (int j = 0; j < 4; ++j) {
          const int lc = wcB + j * 16 + fr;
          ob1[(size_t)(gm + lr) * Q_ + lc] = f2bf(acc[i][j][r] * inv * qm[j]);
        }
      }
  }
}

// PV: a = alpha @ qryT^T (64x128 tile, K=128, no staged K-loop).
// B panel (32KB) staged to LDS once; A (alpha) fragments direct from global;
// epilogue writes all 4 output sections via NONTEMPORAL float4 stores
// (output is never re-read -> bypass L2, keep it for ctxp/qryT reads).
__global__ __launch_bounds__(256) void pv_kernel(
    const unsigned short* __restrict__ alpha, const unsigned short* __restrict__ qryT,
    const unsigned short* __restrict__ ctxp, const float* __restrict__ bvec,
    float* __restrict__ out32) {
  __shared__ __align__(16) unsigned char smem[33792];
  const int tid = threadIdx.x;
  const int lane = tid & 63;
  const int w = tid >> 6;
  const int fr = lane & 15;
  const int fq = lane >> 4;
  const int orig = ((int)blockIdx.x & 7) * 192 + ((int)blockIdx.x >> 3);
  const int bb = orig / 96;
  const int rem = orig % 96;
  const int gm = bb * C_ + (rem / 6) * 64;
  const int gn = (rem % 6) * 128;
  const unsigned short* Ap = alpha + (size_t)gm * Q_;
  const unsigned short* Bp = qryT + ((size_t)bb * H_ + gn) * Q_;
  const int wrA = (w >> 1) * 32;
  const int wcB = (w & 1) * 64;
  unsigned short* Ws = (unsigned short*)smem;

  // stage full B panel (128 x 128 bf16 = 32 KB) via async gload_lds, one drain
#pragma unroll
  for (int kk = 0; kk < 4; ++kk) {
#pragma unroll
    for (int r = 0; r < 2; ++r) {
      const int c = r * 256 + tid;
      const int row = c >> 2, sub = c & 3;
      const unsigned short* g = Bp + (size_t)row * Q_ + kk * 32 + sub * 8;
      unsigned short* l = Ws + kk * 4096 + (size_t)(r * 256 + w * 64) * 8;
      __builtin_amdgcn_global_load_lds(
          (const __attribute__((address_space(1))) void*)g,
          (__attribute__((address_space(3))) void*)l, 16, 0, 0);
    }
  }
  // ctxp tile prefetch in output layout (T14: hides under MFMA phase)
  ushort4 cxr[8];
#pragma unroll
  for (int k = 0; k < 8; ++k) {
    const int f = k * 256 + tid;
    const int row = f >> 5, c4 = (f & 31) << 2;
    cxr[k] = *(const ushort4*)&ctxp[(size_t)(gm + row) * H_ + gn + c4];
  }
  // A (alpha) fragments direct from global — 4 MB buffer, L2-hot
  bf16x8 af[2][4];
#pragma unroll
  for (int i = 0; i < 2; ++i)
#pragma unroll
    for (int kk = 0; kk < 4; ++kk)
      af[i][kk] = *(const bf16x8*)(Ap + (size_t)(wrA + i * 16 + fr) * Q_ + kk * 32 + fq * 8);

  f32x4 acc[2][4];
#pragma unroll
  for (int i = 0; i < 2; ++i)
#pragma unroll
    for (int j = 0; j < 4; ++j)
#pragma unroll
      for (int e = 0; e < 4; ++e) acc[i][j][e] = 0.f;

  __syncthreads();  // B panel resident
#pragma unroll
  for (int kk = 0; kk < 4; ++kk) {
    bf16x8 wf[4];
#pragma unroll
    for (int j = 0; j < 4; ++j)
      wf[j] = *(const bf16x8*)(Ws + kk * 4096 + (wcB + j * 16 + fr) * 32 + fq * 8);
#pragma unroll
    for (int i = 0; i < 2; ++i)
#pragma unroll
      for (int j = 0; j < 4; ++j)
        acc[i][j] = __builtin_amdgcn_mfma_f32_16x16x32_bf16(af[i][kk], wf[j], acc[i][j], 0, 0, 0);
  }
  __syncthreads();  // done reading Ws; reuse as fp32 transpose buffer

  float* tr = (float*)smem;
#pragma unroll
  for (int i = 0; i < 2; ++i)
#pragma unroll
    for (int j = 0; j < 4; ++j)
#pragma unroll
      for (int r = 0; r < 4; ++r)
        tr[(wrA + i * 16 + fq * 4 + r) * 132 + wcB + j * 16 + fr] = acc[i][j][r];
  __syncthreads();
#pragma unroll
  for (int k = 0; k < 8; ++k) {
    const int f = k * 256 + tid;
    const int row = f >> 5, c4 = (f & 31) << 2;
    f32x4 av = *(const f32x4*)&tr[row * 132 + c4];
    const ushort4 cu = cxr[k];
    f32x4 bv = *(const f32x4*)&bvec[bb * H_ + gn + c4];
    const float cx0 = bf2f(cu.x), cx1 = bf2f(cu.y), cx2 = bf2f(cu.z), cx3 = bf2f(cu.w);
    float* rowp = out32 + (size_t)(gm + row) * OSTR + gn;
    f32x4 cxv; cxv[0] = cx0; cxv[1] = cx1; cxv[2] = cx2; cxv[3] = cx3;
    __builtin_nontemporal_store(cxv, (f32x4*)&rowp[c4]);
    __builtin_nontemporal_store(av, (f32x4*)&rowp[H_ + c4]);
    f32x4 cc;
    cc[0] = cx0 * av[0]; cc[1] = cx1 * av[1]; cc[2] = cx2 * av[2]; cc[3] = cx3 * av[3];
    __builtin_nontemporal_store(cc, (f32x4*)&rowp[2 * H_ + c4]);
    f32x4 dd;
    dd[0] = cx0 * bv[0]; dd[1] = cx1 * bv[1]; dd[2] = cx2 * bv[2]; dd[3] = cx3 * bv[3];
    __builtin_nontemporal_store(dd, (f32x4*)&rowp[3 * H_ + c4]);
  }
}

// beta softmax over c (per batch) + bvec[b,p] = sum_c beta[c]*ctx_bf16[b,c,p]
__global__ __launch_bounds__(256) void beta_bvec_kernel(
    const unsigned short* __restrict__ ctxp, const float* __restrict__ q2c,
    const float* __restrict__ cmask, float* __restrict__ bvec) {
  __shared__ float sh[C_];
  __shared__ float red[256];
  const int tid = threadIdx.x;
  const int b = blockIdx.x / 12;
  const int p0 = (blockIdx.x % 12) * 64;
  float v[4];
  float lm = -1e30f;
#pragma unroll
  for (int i = 0; i < 4; ++i) {
    v[i] = q2c[b * C_ + i * 256 + tid];
    lm = fmaxf(lm, v[i]);
  }
  red[tid] = lm;
  __syncthreads();
  for (int off = 128; off > 0; off >>= 1) {
    if (tid < off) red[tid] = fmaxf(red[tid], red[tid + off]);
    __syncthreads();
  }
  const float m = red[0];
  __syncthreads();
  float ls = 0.f;
#pragma unroll
  for (int i = 0; i < 4; ++i) {
    float e = __expf(v[i] - m);
    sh[i * 256 + tid] = e * cmask[b * C_ + i * 256 + tid];
    ls += e;
  }
  red[tid] = ls;
  __syncthreads();
  for (int off = 128; off > 0; off >>= 1) {
    if (tid < off) red[tid] += red[tid + off];
    __syncthreads();
  }
  const float denom = red[0];
  const int pp = tid & 63;
  const int cg = tid >> 6;
  const unsigned short* base = ctxp + ((size_t)(b * C_ + cg)) * H_ + p0 + pp;
  float acc = 0.f;
#pragma unroll 4
  for (int c = cg; c < C_; c += 4) {
    acc += sh[c] * bf2f(*base);
    base += (size_t)4 * H_;
  }
  __syncthreads();
  red[tid] = acc;
  __syncthreads();
  if (tid < 64)
    bvec[b * H_ + p0 + tid] =
        (red[tid] + red[tid + 64] + red[tid + 128] + red[tid + 192]) / denom;
}

extern "C" void kernel_launch(void* const* d_in, const int* in_sizes, int n_in,
                              void* d_out, int out_size, void* d_ws, size_t ws_size,
                              hipStream_t stream) {
  const float* context = (const float*)d_in[0];
  const float* cmask   = (const float*)d_in[1];
  const float* query   = (const float*)d_in[2];
  const float* qmask   = (const float*)d_in[3];
  const float* Wc      = (const float*)d_in[4];
  const float* bc      = (const float*)d_in[5];
  const float* Wq      = (const float*)d_in[6];
  const float* bq      = (const float*)d_in[7];
  const float* w_att   = (const float*)d_in[8];
  float* out = (float*)d_out;

  unsigned short* ws_ctxb = (unsigned short*)d_ws;
  unsigned short* ws_qinb = ws_ctxb + (size_t)B_ * C_ * H_;
  unsigned short* ws_Wcb  = ws_qinb + (size_t)B_ * Q_ * H_;
  unsigned short* ws_Wqb  = ws_Wcb + (size_t)H_ * H_;
  unsigned short* ws_qryW = ws_Wqb + (size_t)H_ * H_;
  unsigned short* ws_qryT = ws_qryW + (size_t)B_ * Q_ * H_;
  unsigned short* ws_ctxp = ws_qryT + (size_t)B_ * H_ * Q_;
  float* ws_q2c  = (float*)(ws_ctxp + (size_t)B_ * C_ * H_);
  float* ws_bvec = ws_q2c + (size_t)B_ * C_;
  unsigned short* ws_alpha = ws_qinb;  // overlays dead qinb+Wcb

  {
    const int n0 = B_ * C_ * H_ / 8;
    const int n1 = B_ * Q_ * H_ / 8;
    const int n2 = H_ * H_ / 8;
    const int n3 = n2;
    const int tot = n0 + n1 + n2 + n3;
    f2bf4_kernel<<<(tot + 255) / 256, 256, 0, stream>>>(
        context, ws_ctxb, n0, query, ws_qinb, n1, Wc, ws_Wcb, n2, Wq, ws_Wqb, n3);
  }
  // qry projection: qryW (w_att folded) + qryT. 96 blocks, qchunk=12.
  gemm_uni<1><<<96, 256, 0, stream>>>(
      ws_qinb, ws_Wqb, bq, ws_qryW, ws_qryT, w_att,
      nullptr, nullptr, nullptr, H_, 12);
  // ctx projection -> bf16 ctxp ONLY. 768 blocks, qchunk=96.
  gemm_uni<0><<<768, 256, 0, stream>>>(
      ws_ctxb, ws_Wcb, bc, ws_ctxp, nullptr, nullptr,
      nullptr, nullptr, nullptr, H_, 96);
  // sim GEMM + fused softmax: alpha bf16 + q2c. 256 blocks (64-row), qchunk=32.
  gemm_uni<2><<<256, 256, 0, stream>>>(
      ws_ctxp, ws_qryW, nullptr, ws_alpha, nullptr, nullptr,
      cmask, qmask, ws_q2c, H_, 32);
  // beta softmax + bvec (reads bf16 ctxp). 192 blocks.
  beta_bvec_kernel<<<B_ * 12, 256, 0, stream>>>(ws_ctxp, ws_q2c, cmask, ws_bvec);
  // PV: writes ALL of out (ctx, a, c, d) nontemporally. 1536 blocks, qchunk=192.
  pv_kernel<<<1536, 256, 0, stream>>>(ws_alpha, ws_qryT, ws_ctxp, ws_bvec, out);
}

// Round 15
// 141.802 us; speedup vs baseline: 1.2225x; 1.0937x over previous
//
#include <hip/hip_runtime.h>
#include <cstdint>

#define B_ 16
#define C_ 1024
#define Q_ 128
#define H_ 768
#define OSTR (4 * H_)  // 3072

typedef __attribute__((ext_vector_type(8))) short bf16x8;
typedef __attribute__((ext_vector_type(4))) float f32x4;
typedef __attribute__((ext_vector_type(4))) int int4v;

__device__ __forceinline__ unsigned short f2bf(float x) {
  union { float f; unsigned u; } v; v.f = x;
  unsigned r = v.u + 0x7FFFu + ((v.u >> 16) & 1u);
  return (unsigned short)(r >> 16);
}
__device__ __forceinline__ unsigned pk2(float a, float b) {
  return (unsigned)f2bf(a) | ((unsigned)f2bf(b) << 16);
}
__device__ __forceinline__ float bf2f(unsigned short u) {
  union { unsigned u; float f; } t; t.u = ((unsigned)u) << 16; return t.f;
}

// four-segment fp32 -> bf16 (context, query, Wc, Wq); NT loads.
__global__ __launch_bounds__(256) void f2bf4_kernel(
    const float* __restrict__ s0, unsigned short* __restrict__ d0, int n0,
    const float* __restrict__ s1, unsigned short* __restrict__ d1, int n1,
    const float* __restrict__ s2, unsigned short* __restrict__ d2, int n2,
    const float* __restrict__ s3, unsigned short* __restrict__ d3, int n3) {
  int i = blockIdx.x * 256 + threadIdx.x;
  const float* s;
  unsigned short* d;
  if (i < n0) { s = s0; d = d0; }
  else if ((i -= n0) < n1) { s = s1; d = d1; }
  else if ((i -= n1) < n2) { s = s2; d = d2; }
  else if ((i -= n2) < n3) { s = s3; d = d3; }
  else return;
  f32x4 a = __builtin_nontemporal_load((const f32x4*)s + 2 * i);
  f32x4 b = __builtin_nontemporal_load((const f32x4*)s + 2 * i + 1);
  int4v o;
  o[0] = (int)pk2(a[0], a[1]); o[1] = (int)pk2(a[2], a[3]);
  o[2] = (int)pk2(b[0], b[1]); o[3] = (int)pk2(b[2], b[3]);
  ((int4v*)d)[i] = o;
}

// Combined projection GEMM, one launch, 864 blocks:
//   blocks [0,768):  ctx proj -> bf16 ctxp (LDS bf16-transpose, int4v stores)
//   blocks [768,864): qry proj -> bf16 qryW=v*watt + bf16 qryT (transposed)
// Both: 128x128 tile, BK=32, global_load_lds, XCD-chunked bijective swizzle.
__global__ __launch_bounds__(256) void proj_kernel(
    const unsigned short* __restrict__ ctxb, const unsigned short* __restrict__ Wcb,
    const float* __restrict__ bc, unsigned short* __restrict__ ctxp,
    const unsigned short* __restrict__ qinb, const unsigned short* __restrict__ Wqb,
    const float* __restrict__ bq, unsigned short* __restrict__ qryW,
    unsigned short* __restrict__ qryT, const float* __restrict__ watt) {
  __shared__ __align__(16) unsigned char smem[33792];
  unsigned short* As = (unsigned short*)smem;
  unsigned short* Ws = (unsigned short*)(smem + 8192);
  const int tid = threadIdx.x;
  const int lane = tid & 63;
  const int w = tid >> 6;
  const int bid = (int)blockIdx.x;
  const bool isC = bid < 768;
  int orig, gm, gn;
  const unsigned short *Ap, *Bp;
  const float* bias;
  if (isC) {
    orig = (bid & 7) * 96 + (bid >> 3);
    gm = (orig / 6) * 128; gn = (orig % 6) * 128;
    Ap = ctxb + (size_t)gm * H_; Bp = Wcb + (size_t)gn * H_; bias = bc;
  } else {
    const int b2 = bid - 768;
    orig = (b2 & 7) * 12 + (b2 >> 3);
    gm = (orig / 6) * 128; gn = (orig % 6) * 128;
    Ap = qinb + (size_t)gm * H_; Bp = Wqb + (size_t)gn * H_; bias = bq;
  }
  const int wrA = (w >> 1) * 64;
  const int wcB = (w & 1) * 64;
  const int fr = lane & 15;
  const int fq = lane >> 4;

  auto stage128 = [&](const unsigned short* __restrict__ G, unsigned short* S, int k0) {
#pragma unroll
    for (int r = 0; r < 2; ++r) {
      const int c = r * 256 + tid;
      const int row = c >> 2, sub = c & 3;
      const unsigned short* g = G + (size_t)row * H_ + k0 + sub * 8;
      unsigned short* l = S + (size_t)(r * 256 + w * 64) * 8;  // wave-uniform base
      __builtin_amdgcn_global_load_lds(
          (const __attribute__((address_space(1))) void*)g,
          (__attribute__((address_space(3))) void*)l, 16, 0, 0);
    }
  };

  f32x4 acc[4][4];
#pragma unroll
  for (int i = 0; i < 4; ++i)
#pragma unroll
    for (int j = 0; j < 4; ++j)
#pragma unroll
      for (int e = 0; e < 4; ++e) acc[i][j][e] = 0.f;

  for (int k0 = 0; k0 < H_; k0 += 32) {
    stage128(Ap, As, k0);
    stage128(Bp, Ws, k0);
    __syncthreads();
    bf16x8 af[4], wf[4];
#pragma unroll
    for (int i = 0; i < 4; ++i)
      af[i] = *(const bf16x8*)(As + (wrA + i * 16 + fr) * 32 + fq * 8);
#pragma unroll
    for (int j = 0; j < 4; ++j)
      wf[j] = *(const bf16x8*)(Ws + (wcB + j * 16 + fr) * 32 + fq * 8);
#pragma unroll
    for (int i = 0; i < 4; ++i)
#pragma unroll
      for (int j = 0; j < 4; ++j)
        acc[i][j] = __builtin_amdgcn_mfma_f32_16x16x32_bf16(af[i], wf[j], acc[i][j], 0, 0, 0);
    __syncthreads();
  }

  if (isC) {
    // bf16 transpose in LDS -> coalesced int4v stores of ctxp
    unsigned short* tr16 = (unsigned short*)smem;
    float bj[4];
#pragma unroll
    for (int j = 0; j < 4; ++j) bj[j] = bias[gn + wcB + j * 16 + fr];
#pragma unroll
    for (int i = 0; i < 4; ++i)
#pragma unroll
      for (int j = 0; j < 4; ++j)
#pragma unroll
        for (int r = 0; r < 4; ++r)
          tr16[(wrA + i * 16 + fq * 4 + r) * 132 + wcB + j * 16 + fr] =
              f2bf(acc[i][j][r] + bj[j]);
    __syncthreads();
#pragma unroll
    for (int k = 0; k < 8; ++k) {
      const int f = k * 256 + tid;
      const int row = f >> 4, c8 = (f & 15) << 3;
      int4v v = *(const int4v*)&tr16[row * 132 + c8];
      *(int4v*)&ctxp[(size_t)(gm + row) * H_ + gn + c8] = v;
    }
  } else {
#pragma unroll
    for (int i = 0; i < 4; ++i) {
#pragma unroll
      for (int j = 0; j < 4; ++j) {
        const int n = gn + wcB + j * 16 + fr;
        const float bias_n = bias[n];
        const float wv = watt[n];
        ushort4 t4;
#pragma unroll
        for (int r = 0; r < 4; ++r) {
          const size_t m = (size_t)gm + wrA + i * 16 + fq * 4 + r;
          float v = acc[i][j][r] + bias_n;
          qryW[m * H_ + n] = f2bf(v * wv);
          (&t4.x)[r] = f2bf(v);
        }
        const int bidx = gm >> 7;
        const int q0 = wrA + i * 16 + fq * 4;
        *(ushort4*)(qryT + ((size_t)bidx * H_ + n) * Q_ + q0) = t4;
      }
    }
  }
}

// sim GEMM (64x128, full q) -> fused row-softmax -> bf16 alpha + q2c
__global__ __launch_bounds__(256) void sim_kernel(
    const unsigned short* __restrict__ A, const unsigned short* __restrict__ Bm,
    unsigned short* __restrict__ alpha, const float* __restrict__ cmask,
    const float* __restrict__ qmask, float* __restrict__ q2c) {
  __shared__ __align__(16) unsigned char smem[16384];
  __shared__ float pmS[2][64];
  __shared__ float psS[2][64];
  unsigned short* As = (unsigned short*)smem;
  unsigned short* Ws = (unsigned short*)(smem + 4096);
  const int tid = threadIdx.x;
  const int lane = tid & 63;
  const int w = tid >> 6;
  const int orig = ((int)blockIdx.x & 7) * 32 + ((int)blockIdx.x >> 3);
  const int bb = orig >> 4;
  const int gm = bb * C_ + (orig & 15) * 64;
  const int wrA = (w >> 1) * 32;
  const int wcB = (w & 1) * 64;
  const int fr = lane & 15;
  const int fq = lane >> 4;
  const unsigned short* Ap = A + (size_t)gm * H_;
  const unsigned short* Bp = Bm + (size_t)bb * Q_ * H_;

  f32x4 acc[2][4];
#pragma unroll
  for (int i = 0; i < 2; ++i)
#pragma unroll
    for (int j = 0; j < 4; ++j)
#pragma unroll
      for (int e = 0; e < 4; ++e) acc[i][j][e] = 0.f;

  for (int k0 = 0; k0 < H_; k0 += 32) {
    {
      const int row = tid >> 2, sub = tid & 3;
      const unsigned short* g = Ap + (size_t)row * H_ + k0 + sub * 8;
      unsigned short* l = As + (size_t)(w * 64) * 8;
      __builtin_amdgcn_global_load_lds(
          (const __attribute__((address_space(1))) void*)g,
          (__attribute__((address_space(3))) void*)l, 16, 0, 0);
    }
#pragma unroll
    for (int r = 0; r < 2; ++r) {
      const int c = r * 256 + tid;
      const int row = c >> 2, sub = c & 3;
      const unsigned short* g = Bp + (size_t)row * H_ + k0 + sub * 8;
      unsigned short* l = Ws + (size_t)(r * 256 + w * 64) * 8;
      __builtin_amdgcn_global_load_lds(
          (const __attribute__((address_space(1))) void*)g,
          (__attribute__((address_space(3))) void*)l, 16, 0, 0);
    }
    __syncthreads();
    bf16x8 af[2], wf[4];
#pragma unroll
    for (int i = 0; i < 2; ++i)
      af[i] = *(const bf16x8*)(As + (wrA + i * 16 + fr) * 32 + fq * 8);
#pragma unroll
    for (int j = 0; j < 4; ++j)
      wf[j] = *(const bf16x8*)(Ws + (wcB + j * 16 + fr) * 32 + fq * 8);
#pragma unroll
    for (int i = 0; i < 2; ++i)
#pragma unroll
      for (int j = 0; j < 4; ++j)
        acc[i][j] = __builtin_amdgcn_mfma_f32_16x16x32_bf16(af[i], wf[j], acc[i][j], 0, 0, 0);
    __syncthreads();
  }

  float red[2][4];
#pragma unroll
  for (int i = 0; i < 2; ++i)
#pragma unroll
    for (int r = 0; r < 4; ++r) {
      float mx = acc[i][0][r];
#pragma unroll
      for (int j = 1; j < 4; ++j) mx = fmaxf(mx, acc[i][j][r]);
      mx = fmaxf(mx, __shfl_xor(mx, 1));
      mx = fmaxf(mx, __shfl_xor(mx, 2));
      mx = fmaxf(mx, __shfl_xor(mx, 4));
      mx = fmaxf(mx, __shfl_xor(mx, 8));
      if (fr == 0) pmS[w & 1][wrA + i * 16 + fq * 4 + r] = mx;
    }
  __syncthreads();
  float qm[4];
#pragma unroll
  for (int j = 0; j < 4; ++j) qm[j] = qmask[bb * Q_ + wcB + j * 16 + fr];
#pragma unroll
  for (int i = 0; i < 2; ++i)
#pragma unroll
    for (int r = 0; r < 4; ++r) {
      const int lr = wrA + i * 16 + fq * 4 + r;
      const float M = fmaxf(pmS[0][lr], pmS[1][lr]);
      if ((w & 1) == 0 && fr == 0) q2c[gm + lr] = M;  // b_att cancels in both softmaxes
      float s = 0.f;
#pragma unroll
      for (int j = 0; j < 4; ++j) {
        acc[i][j][r] = __expf(acc[i][j][r] - M);
        s += acc[i][j][r];
      }
      s += __shfl_xor(s, 1); s += __shfl_xor(s, 2);
      s += __shfl_xor(s, 4); s += __shfl_xor(s, 8);
      if (fr == 0) psS[w & 1][lr] = s;
    }
  __syncthreads();
#pragma unroll
  for (int i = 0; i < 2; ++i)
#pragma unroll
    for (int r = 0; r < 4; ++r) {
      const int lr = wrA + i * 16 + fq * 4 + r;
      const float S = psS[0][lr] + psS[1][lr];
      const float inv = cmask[gm + lr] / S;
#pragma unroll
      for (int j = 0; j < 4; ++j) {
        const int lc = wcB + j * 16 + fr;
        alpha[(size_t)(gm + lr) * Q_ + lc] = f2bf(acc[i][j][r] * inv * qm[j]);
      }
    }
}

// PV: a = alpha @ qryT^T, 32x128 tile (grid 3072), K=128, no staged K-loop.
// B panel (32KB) staged once; alpha frags direct from global (L2-hot);
// all 4 output sections written via NT float4 stores.
__global__ __launch_bounds__(256) void pv_kernel(
    const unsigned short* __restrict__ alpha, const unsigned short* __restrict__ qryT,
    const unsigned short* __restrict__ ctxp, const float* __restrict__ bvec,
    float* __restrict__ out32) {
  __shared__ __align__(16) unsigned char smem[33792];
  const int tid = threadIdx.x;
  const int lane = tid & 63;
  const int w = tid >> 6;
  const int fr = lane & 15;
  const int fq = lane >> 4;
  const int orig = ((int)blockIdx.x & 7) * 384 + ((int)blockIdx.x >> 3);
  const int bb = orig / 192;
  const int rem = orig % 192;
  const int gm = bb * C_ + (rem / 6) * 32;
  const int gn = (rem % 6) * 128;
  const unsigned short* Ap = alpha + (size_t)gm * Q_;
  const unsigned short* Bp = qryT + ((size_t)bb * H_ + gn) * Q_;
  const int wrA = (w >> 1) * 16;
  const int wcB = (w & 1) * 64;
  unsigned short* Ws = (unsigned short*)smem;

  // stage full B panel (128 x 128 bf16 = 32 KB) via async gload_lds, one drain
#pragma unroll
  for (int kk = 0; kk < 4; ++kk) {
#pragma unroll
    for (int r = 0; r < 2; ++r) {
      const int c = r * 256 + tid;
      const int row = c >> 2, sub = c & 3;
      const unsigned short* g = Bp + (size_t)row * Q_ + kk * 32 + sub * 8;
      unsigned short* l = Ws + kk * 4096 + (size_t)(r * 256 + w * 64) * 8;
      __builtin_amdgcn_global_load_lds(
          (const __attribute__((address_space(1))) void*)g,
          (__attribute__((address_space(3))) void*)l, 16, 0, 0);
    }
  }
  // ctxp tile prefetch in output layout (hides under MFMA phase)
  ushort4 cxr[4];
#pragma unroll
  for (int k = 0; k < 4; ++k) {
    const int f = k * 256 + tid;
    const int row = f >> 5, c4 = (f & 31) << 2;
    cxr[k] = *(const ushort4*)&ctxp[(size_t)(gm + row) * H_ + gn + c4];
  }
  // alpha fragments direct from global
  bf16x8 af[4];
#pragma unroll
  for (int kk = 0; kk < 4; ++kk)
    af[kk] = *(const bf16x8*)(Ap + (size_t)(wrA + fr) * Q_ + kk * 32 + fq * 8);

  f32x4 acc[4];
#pragma unroll
  for (int j = 0; j < 4; ++j)
#pragma unroll
    for (int e = 0; e < 4; ++e) acc[j][e] = 0.f;

  __syncthreads();  // B panel resident
#pragma unroll
  for (int kk = 0; kk < 4; ++kk) {
    bf16x8 wf[4];
#pragma unroll
    for (int j = 0; j < 4; ++j)
      wf[j] = *(const bf16x8*)(Ws + kk * 4096 + (wcB + j * 16 + fr) * 32 + fq * 8);
#pragma unroll
    for (int j = 0; j < 4; ++j)
      acc[j] = __builtin_amdgcn_mfma_f32_16x16x32_bf16(af[kk], wf[j], acc[j], 0, 0, 0);
  }
  __syncthreads();  // done reading Ws; reuse as fp32 transpose buffer

  float* tr = (float*)smem;
#pragma unroll
  for (int j = 0; j < 4; ++j)
#pragma unroll
    for (int r = 0; r < 4; ++r)
      tr[(wrA + fq * 4 + r) * 132 + wcB + j * 16 + fr] = acc[j][r];
  __syncthreads();
#pragma unroll
  for (int k = 0; k < 4; ++k) {
    const int f = k * 256 + tid;
    const int row = f >> 5, c4 = (f & 31) << 2;
    f32x4 av = *(const f32x4*)&tr[row * 132 + c4];
    const ushort4 cu = cxr[k];
    f32x4 bv = *(const f32x4*)&bvec[bb * H_ + gn + c4];
    const float cx0 = bf2f(cu.x), cx1 = bf2f(cu.y), cx2 = bf2f(cu.z), cx3 = bf2f(cu.w);
    float* rowp = out32 + (size_t)(gm + row) * OSTR + gn;
    f32x4 cxv; cxv[0] = cx0; cxv[1] = cx1; cxv[2] = cx2; cxv[3] = cx3;
    __builtin_nontemporal_store(cxv, (f32x4*)&rowp[c4]);
    __builtin_nontemporal_store(av, (f32x4*)&rowp[H_ + c4]);
    f32x4 cc;
    cc[0] = cx0 * av[0]; cc[1] = cx1 * av[1]; cc[2] = cx2 * av[2]; cc[3] = cx3 * av[3];
    __builtin_nontemporal_store(cc, (f32x4*)&rowp[2 * H_ + c4]);
    f32x4 dd;
    dd[0] = cx0 * bv[0]; dd[1] = cx1 * bv[1]; dd[2] = cx2 * bv[2]; dd[3] = cx3 * bv[3];
    __builtin_nontemporal_store(dd, (f32x4*)&rowp[3 * H_ + c4]);
  }
}

// beta softmax over c (per batch) + bvec[b,p] = sum_c beta[c]*ctx_bf16[b,c,p]
__global__ __launch_bounds__(256) void beta_bvec_kernel(
    const unsigned short* __restrict__ ctxp, const float* __restrict__ q2c,
    const float* __restrict__ cmask, float* __restrict__ bvec) {
  __shared__ float sh[C_];
  __shared__ float red[256];
  const int tid = threadIdx.x;
  const int b = blockIdx.x / 12;
  const int p0 = (blockIdx.x % 12) * 64;
  float v[4];
  float lm = -1e30f;
#pragma unroll
  for (int i = 0; i < 4; ++i) {
    v[i] = q2c[b * C_ + i * 256 + tid];
    lm = fmaxf(lm, v[i]);
  }
  red[tid] = lm;
  __syncthreads();
  for (int off = 128; off > 0; off >>= 1) {
    if (tid < off) red[tid] = fmaxf(red[tid], red[tid + off]);
    __syncthreads();
  }
  const float m = red[0];
  __syncthreads();
  float ls = 0.f;
#pragma unroll
  for (int i = 0; i < 4; ++i) {
    float e = __expf(v[i] - m);
    sh[i * 256 + tid] = e * cmask[b * C_ + i * 256 + tid];
    ls += e;
  }
  red[tid] = ls;
  __syncthreads();
  for (int off = 128; off > 0; off >>= 1) {
    if (tid < off) red[tid] += red[tid + off];
    __syncthreads();
  }
  const float denom = red[0];
  const int pp = tid & 63;
  const int cg = tid >> 6;
  const unsigned short* base = ctxp + ((size_t)(b * C_ + cg)) * H_ + p0 + pp;
  float acc = 0.f;
#pragma unroll 4
  for (int c = cg; c < C_; c += 4) {
    acc += sh[c] * bf2f(*base);
    base += (size_t)4 * H_;
  }
  __syncthreads();
  red[tid] = acc;
  __syncthreads();
  if (tid < 64)
    bvec[b * H_ + p0 + tid] =
        (red[tid] + red[tid + 64] + red[tid + 128] + red[tid + 192]) / denom;
}

extern "C" void kernel_launch(void* const* d_in, const int* in_sizes, int n_in,
                              void* d_out, int out_size, void* d_ws, size_t ws_size,
                              hipStream_t stream) {
  const float* context = (const float*)d_in[0];
  const float* cmask   = (const float*)d_in[1];
  const float* query   = (const float*)d_in[2];
  const float* qmask   = (const float*)d_in[3];
  const float* Wc      = (const float*)d_in[4];
  const float* bc      = (const float*)d_in[5];
  const float* Wq      = (const float*)d_in[6];
  const float* bq      = (const float*)d_in[7];
  const float* w_att   = (const float*)d_in[8];
  float* out = (float*)d_out;

  unsigned short* ws_ctxb = (unsigned short*)d_ws;
  unsigned short* ws_qinb = ws_ctxb + (size_t)B_ * C_ * H_;
  unsigned short* ws_Wcb  = ws_qinb + (size_t)B_ * Q_ * H_;
  unsigned short* ws_Wqb  = ws_Wcb + (size_t)H_ * H_;
  unsigned short* ws_qryW = ws_Wqb + (size_t)H_ * H_;
  unsigned short* ws_qryT = ws_qryW + (size_t)B_ * Q_ * H_;
  unsigned short* ws_ctxp = ws_qryT + (size_t)B_ * H_ * Q_;
  float* ws_q2c  = (float*)(ws_ctxp + (size_t)B_ * C_ * H_);
  float* ws_bvec = ws_q2c + (size_t)B_ * C_;
  unsigned short* ws_alpha = ws_qinb;  // overlays dead qinb+Wcb

  {
    const int n0 = B_ * C_ * H_ / 8;
    const int n1 = B_ * Q_ * H_ / 8;
    const int n2 = H_ * H_ / 8;
    const int n3 = n2;
    const int tot = n0 + n1 + n2 + n3;
    f2bf4_kernel<<<(tot + 255) / 256, 256, 0, stream>>>(
        context, ws_ctxb, n0, query, ws_qinb, n1, Wc, ws_Wcb, n2, Wq, ws_Wqb, n3);
  }
  // combined projections: ctx (768 blocks) + qry (96 blocks), one launch.
  proj_kernel<<<864, 256, 0, stream>>>(
      ws_ctxb, ws_Wcb, bc, ws_ctxp, ws_qinb, ws_Wqb, bq, ws_qryW, ws_qryT, w_att);
  // sim GEMM + fused softmax: alpha bf16 + q2c. 256 blocks (64-row).
  sim_kernel<<<256, 256, 0, stream>>>(
      ws_ctxp, ws_qryW, ws_alpha, cmask, qmask, ws_q2c);
  // beta softmax + bvec (reads bf16 ctxp). 192 blocks.
  beta_bvec_kernel<<<B_ * 12, 256, 0, stream>>>(ws_ctxp, ws_q2c, cmask, ws_bvec);
  // PV: writes ALL of out (ctx, a, c, d) nontemporally. 3072 blocks (32-row).
  pv_kernel<<<3072, 256, 0, stream>>>(ws_alpha, ws_qryT, ws_ctxp, ws_bvec, out);
}